// Round 2
// baseline (81.215 us; speedup 1.0000x reference)
//
#include <hip/hip_runtime.h>

#define SEQ 200
#define SEQ_PAD 256   // next pow2 for bitonic sort
#define DIM 512

// ---------------- Kernel A: global Frobenius-norm (sum of squares) ----------
__global__ __launch_bounds__(256) void ssq_kernel(const int* __restrict__ xs,
                                                  const float* __restrict__ freqs,
                                                  double* __restrict__ ssq,
                                                  int n) {
    double acc = 0.0;
    for (int i = blockIdx.x * blockDim.x + threadIdx.x; i < n;
         i += gridDim.x * blockDim.x) {
        float f = freqs[xs[i]];
        acc += (double)f * (double)f;
    }
    for (int off = 32; off > 0; off >>= 1)
        acc += __shfl_down(acc, off, 64);
    __shared__ double s_w[4];
    int lane = threadIdx.x & 63;
    int wave = threadIdx.x >> 6;
    if (lane == 0) s_w[wave] = acc;
    __syncthreads();
    if (threadIdx.x == 0) {
        double t = s_w[0] + s_w[1] + s_w[2] + s_w[3];
        atomicAdd(ssq, t);
    }
}

// ---------------- Kernel B: scaled gather-pool with per-block index sort ----
// One block per batch row b. 512 threads = 4 groups x 128 lanes.
// Indices are bitonic-sorted ascending per block so that all 1024 co-resident
// blocks sweep the vocab table in ascending order together -> row reuse
// across blocks becomes an L3 hit inside the sweep window instead of a
// second HBM fetch.
__global__ __launch_bounds__(512) void pool_kernel(const int* __restrict__ xs,
                                                   const float* __restrict__ W,
                                                   const float* __restrict__ freqs,
                                                   const double* __restrict__ ssq,
                                                   float* __restrict__ out) {
    __shared__ unsigned s_key[SEQ_PAD];   // (idx<<8) | orig_l  (idx<100000 -> fits)
    __shared__ float    s_scl[SEQ];       // scale per ORIGINAL l
    __shared__ float    s_part[3][DIM];   // partials for groups 1..3

    const int b   = blockIdx.x;
    const int tid = threadIdx.x;

    const float inv_norm = (float)(1.0 / sqrt(ssq[0]));

    // stage indices + scales; pack keys for sorting
    for (int l = tid; l < SEQ_PAD; l += 512) {
        if (l < SEQ) {
            int idx  = xs[b * SEQ + l];
            s_key[l] = ((unsigned)idx << 8) | (unsigned)l;
            s_scl[l] = freqs[idx] * inv_norm;
        } else {
            s_key[l] = 0xFFFFFFFFu;  // sentinel sorts to the end
        }
    }

    // bitonic sort of 256 keys (threads 0..255 each own one slot)
    for (unsigned k = 2; k <= SEQ_PAD; k <<= 1) {
        for (unsigned j = k >> 1; j > 0; j >>= 1) {
            __syncthreads();
            if (tid < SEQ_PAD) {
                unsigned i = (unsigned)tid, ixj = i ^ j;
                if (ixj > i) {
                    unsigned a = s_key[i], c = s_key[ixj];
                    bool up = ((i & k) == 0);
                    if ((a > c) == up) { s_key[i] = c; s_key[ixj] = a; }
                }
            }
        }
    }
    __syncthreads();

    const int group   = tid >> 7;    // 0..3
    const int lane128 = tid & 127;   // float4 slice id
    const int col4    = lane128 * 4;

    float4 acc = make_float4(0.f, 0.f, 0.f, 0.f);

    // groups interleave over the SORTED order -> whole block (and whole grid)
    // walks vocab ascending
    #pragma unroll 4
    for (int l = group; l < SEQ; l += 4) {
        const unsigned key = s_key[l];
        const int   idx    = (int)(key >> 8);
        const float s      = s_scl[key & 255u];
        const float4 w     = *reinterpret_cast<const float4*>(
            W + (size_t)idx * DIM + col4);
        acc.x += s * w.x;
        acc.y += s * w.y;
        acc.z += s * w.z;
        acc.w += s * w.w;
    }

    if (group > 0)
        *reinterpret_cast<float4*>(&s_part[group - 1][col4]) = acc;
    __syncthreads();

    if (group == 0) {
        for (int g = 0; g < 3; ++g) {
            const float4 p = *reinterpret_cast<const float4*>(&s_part[g][col4]);
            acc.x += p.x; acc.y += p.y; acc.z += p.z; acc.w += p.w;
        }
        *reinterpret_cast<float4*>(out + (size_t)b * DIM + col4) = acc;
    }
}

extern "C" void kernel_launch(void* const* d_in, const int* in_sizes, int n_in,
                              void* d_out, int out_size, void* d_ws, size_t ws_size,
                              hipStream_t stream) {
    const int*   xs    = (const int*)d_in[0];    // [1024, 200] int32
    const float* W     = (const float*)d_in[1];  // [100000, 512] f32
    const float* freqs = (const float*)d_in[2];  // [100000] f32
    float* out = (float*)d_out;                  // [1024, 512] f32
    double* ssq = (double*)d_ws;

    const int n   = in_sizes[0];     // 204800
    const int bsz = n / SEQ;         // 1024

    hipMemsetAsync(d_ws, 0, sizeof(double), stream);
    ssq_kernel<<<400, 256, 0, stream>>>(xs, freqs, ssq, n);
    pool_kernel<<<bsz, 512, 0, stream>>>(xs, W, freqs, ssq, out);
}

// Round 3
// 74.924 us; speedup vs baseline: 1.0840x; 1.0840x over previous
//
#include <hip/hip_runtime.h>

#define SEQ 200
#define SEQ_PAD 256   // next pow2 for bitonic sort
#define DIM 512
#define NPHASE 16     // vocab-range phases: ~12.8 MB of table per phase

// ---------------- Kernel A: global Frobenius-norm (sum of squares) ----------
__global__ __launch_bounds__(256) void ssq_kernel(const int* __restrict__ xs,
                                                  const float* __restrict__ freqs,
                                                  double* __restrict__ ssq,
                                                  int n) {
    double acc = 0.0;
    for (int i = blockIdx.x * blockDim.x + threadIdx.x; i < n;
         i += gridDim.x * blockDim.x) {
        float f = freqs[xs[i]];
        acc += (double)f * (double)f;
    }
    for (int off = 32; off > 0; off >>= 1)
        acc += __shfl_down(acc, off, 64);
    __shared__ double s_w[4];
    int lane = threadIdx.x & 63;
    int wave = threadIdx.x >> 6;
    if (lane == 0) s_w[wave] = acc;
    __syncthreads();
    if (threadIdx.x == 0) {
        double t = s_w[0] + s_w[1] + s_w[2] + s_w[3];
        atomicAdd(ssq, t);
    }
}

// ---------------- Kernel B: phased sorted gather-pool ------------------------
// One block per batch row. Indices bitonic-sorted, then processed in NPHASE
// vocab-VALUE ranges with a block barrier between ranges. All 1024 blocks are
// co-resident (4/CU), so the grid sweeps the 205 MB table range-by-range:
// first touch of a row misses to HBM, repeat touches (~2.05 uses/row) hit the
// L3 window. Convoy is self-stabilizing: leaders miss (slow), laggards hit
// (fast).
__global__ __launch_bounds__(512) void pool_kernel(const int* __restrict__ xs,
                                                   const float* __restrict__ W,
                                                   const float* __restrict__ freqs,
                                                   const double* __restrict__ ssq,
                                                   float* __restrict__ out,
                                                   int vocab) {
    __shared__ unsigned s_key[SEQ_PAD];   // (idx<<8) | orig_l
    __shared__ float    s_scl[SEQ];       // scale per ORIGINAL l
    __shared__ int      s_ph[NPHASE + 1]; // phase start offsets in sorted order
    __shared__ float    s_part[3][DIM];   // partials for groups 1..3

    const int b   = blockIdx.x;
    const int tid = threadIdx.x;

    const float inv_norm = (float)(1.0 / sqrt(ssq[0]));

    for (int l = tid; l < SEQ_PAD; l += 512) {
        if (l < SEQ) {
            int idx  = xs[b * SEQ + l];
            s_key[l] = ((unsigned)idx << 8) | (unsigned)l;
            s_scl[l] = freqs[idx] * inv_norm;
        } else {
            s_key[l] = 0xFFFFFFFFu;  // sentinel: sorts to the end
        }
    }

    // bitonic sort of 256 keys (threads 0..255 each own one slot)
    for (unsigned k = 2; k <= SEQ_PAD; k <<= 1) {
        for (unsigned j = k >> 1; j > 0; j >>= 1) {
            __syncthreads();
            if (tid < SEQ_PAD) {
                unsigned i = (unsigned)tid, ixj = i ^ j;
                if (ixj > i) {
                    unsigned a = s_key[i], c = s_key[ixj];
                    bool up = ((i & k) == 0);
                    if ((a > c) == up) { s_key[i] = c; s_key[ixj] = a; }
                }
            }
        }
    }
    __syncthreads();

    // phase boundaries: lower_bound of each vocab-range start in sorted keys
    if (tid <= NPHASE) {
        unsigned bound = (unsigned)(((unsigned long long)vocab * (unsigned)tid)
                                    / NPHASE) << 8;
        int lo = 0, hi = SEQ_PAD;
        while (lo < hi) {
            int mid = (lo + hi) >> 1;
            if (s_key[mid] < bound) lo = mid + 1; else hi = mid;
        }
        s_ph[tid] = lo;
    }
    __syncthreads();

    const int group   = tid >> 7;    // 0..3
    const int lane128 = tid & 127;   // float4 slice id
    const int col4    = lane128 * 4;

    float4 acc = make_float4(0.f, 0.f, 0.f, 0.f);

    for (int p = 0; p < NPHASE; ++p) {
        const int beg = s_ph[p];
        const int end = s_ph[p + 1];
        for (int l = beg + group; l < end; l += 4) {
            const unsigned key = s_key[l];
            const int   idx    = (int)(key >> 8);
            const float s      = s_scl[key & 255u];
            const float4 w     = *reinterpret_cast<const float4*>(
                W + (size_t)idx * DIM + col4);
            acc.x += s * w.x;
            acc.y += s * w.y;
            acc.z += s * w.z;
            acc.w += s * w.w;
        }
        __syncthreads();   // keep the block (and the convoy) inside one range
    }

    if (group > 0)
        *reinterpret_cast<float4*>(&s_part[group - 1][col4]) = acc;
    __syncthreads();

    if (group == 0) {
        for (int g = 0; g < 3; ++g) {
            const float4 p4 = *reinterpret_cast<const float4*>(&s_part[g][col4]);
            acc.x += p4.x; acc.y += p4.y; acc.z += p4.z; acc.w += p4.w;
        }
        *reinterpret_cast<float4*>(out + (size_t)b * DIM + col4) = acc;
    }
}

extern "C" void kernel_launch(void* const* d_in, const int* in_sizes, int n_in,
                              void* d_out, int out_size, void* d_ws, size_t ws_size,
                              hipStream_t stream) {
    const int*   xs    = (const int*)d_in[0];    // [1024, 200] int32
    const float* W     = (const float*)d_in[1];  // [100000, 512] f32
    const float* freqs = (const float*)d_in[2];  // [100000] f32
    float* out = (float*)d_out;                  // [1024, 512] f32
    double* ssq = (double*)d_ws;

    const int n     = in_sizes[0];   // 204800
    const int bsz   = n / SEQ;       // 1024
    const int vocab = in_sizes[2];   // 100000

    hipMemsetAsync(d_ws, 0, sizeof(double), stream);
    ssq_kernel<<<400, 256, 0, stream>>>(xs, freqs, ssq, n);
    pool_kernel<<<bsz, 512, 0, stream>>>(xs, W, freqs, ssq, out, vocab);
}